// Round 9
// baseline (1083.009 us; speedup 1.0000x reference)
//
#include <hip/hip_runtime.h>
#include <math.h>

#define TPB 256

typedef short bf16x8 __attribute__((ext_vector_type(8)));
typedef unsigned short u16x8 __attribute__((ext_vector_type(8)));
typedef float f32x4 __attribute__((ext_vector_type(4)));

__device__ __forceinline__ float bf2f(unsigned short u) {
  union { unsigned int i; float f; } c;
  c.i = ((unsigned int)u) << 16;
  return c.f;
}
__device__ __forceinline__ unsigned short f2bf(float f) {
  union { float f; unsigned int i; } c;
  c.f = f;
  unsigned int r = c.i + 0x7FFFu + ((c.i >> 16) & 1u);
  return (unsigned short)(r >> 16);
}

// ---------------- CSR build ----------------

__global__ __launch_bounds__(TPB) void zero_cnt_k(int* __restrict__ cnt, int N) {
  int i = blockIdx.x * TPB + threadIdx.x;
  if (i < N) cnt[i] = 0;
}

__global__ __launch_bounds__(TPB) void count_k(const int* __restrict__ dstv,
                                               int* __restrict__ cnt, int E) {
  int e = blockIdx.x * TPB + threadIdx.x;
  if (e < E) atomicAdd(&cnt[dstv[e]], 1);
}

__global__ __launch_bounds__(TPB) void scan1_k(const int* __restrict__ cnt,
                                               int* __restrict__ excl,
                                               int* __restrict__ blk_sums, int N) {
  __shared__ int sh[TPB];
  int b = blockIdx.x, tid = threadIdx.x;
  int base = b * 1024 + tid * 4;
  int v[4];
  int sum = 0;
#pragma unroll
  for (int j = 0; j < 4; ++j) {
    int i = base + j;
    v[j] = (i < N) ? cnt[i] : 0;
    sum += v[j];
  }
  sh[tid] = sum;
  __syncthreads();
  for (int off = 1; off < TPB; off <<= 1) {
    int t = (tid >= off) ? sh[tid - off] : 0;
    __syncthreads();
    sh[tid] += t;
    __syncthreads();
  }
  if (tid == TPB - 1) blk_sums[b] = sh[TPB - 1];
  int run = (tid > 0) ? sh[tid - 1] : 0;
#pragma unroll
  for (int j = 0; j < 4; ++j) {
    int i = base + j;
    if (i < N) excl[i] = run;
    run += v[j];
  }
}

__global__ __launch_bounds__(TPB) void scan2_k(int* __restrict__ blk_sums, int NB) {
  __shared__ int sh[TPB];
  int tid = threadIdx.x;
  sh[tid] = (tid < NB) ? blk_sums[tid] : 0;
  __syncthreads();
  for (int off = 1; off < TPB; off <<= 1) {
    int t = (tid >= off) ? sh[tid - off] : 0;
    __syncthreads();
    sh[tid] += t;
    __syncthreads();
  }
  int ex = (tid > 0) ? sh[tid - 1] : 0;
  if (tid < NB) blk_sums[tid] = ex;
}

__global__ __launch_bounds__(TPB) void finalize_k(int* __restrict__ row_ptr,
                                                  const int* __restrict__ blk_sums,
                                                  int* __restrict__ cursor,
                                                  const int* __restrict__ cnt,
                                                  float* __restrict__ dis, int N, int E) {
  int i = blockIdx.x * TPB + threadIdx.x;
  if (i < N) {
    int r = row_ptr[i] + blk_sums[i >> 10];
    row_ptr[i] = r;
    cursor[i] = r;
    dis[i] = rsqrtf((float)(cnt[i] + 1));
  }
  if (blockIdx.x == 0 && threadIdx.x == 0) row_ptr[N] = E;
}

__global__ __launch_bounds__(TPB) void fill_k(const int* __restrict__ srcv,
                                              const int* __restrict__ dstv,
                                              int* __restrict__ cursor,
                                              int* __restrict__ col_src, int E) {
  int e = blockIdx.x * TPB + threadIdx.x;
  if (e < E) {
    int d = dstv[e];
    int pos = atomicAdd(&cursor[d], 1);
    col_src[pos] = srcv[e];
  }
}

// ---------------- weight transposes ----------------

__global__ __launch_bounds__(TPB) void wt_k(const float* __restrict__ W,
                                            unsigned short* __restrict__ Wt) {
  int idx = blockIdx.x * TPB + threadIdx.x;
  int n = idx >> 8, k = idx & 255;
  Wt[n * 256 + k] = f2bf(W[k * 256 + n]);
}

__global__ __launch_bounds__(TPB) void wot_k(const float* __restrict__ Wo,
                                             unsigned short* __restrict__ Wot) {
  int idx = blockIdx.x * TPB + threadIdx.x;  // 16384 total
  int n = idx >> 8, k = idx & 255;
  Wot[n * 256 + k] = f2bf(Wo[k * 64 + n]);
}

// ---------------- streaming MFMA GEMM: C[M,256] = dis[row]*(A @ Bt^T) ----------------
// Full weight Bt (256x256 bf16 = 128 KB) staged once in LDS (XOR-swizzled),
// ONE barrier, then each wave independently streams 16-row tiles (no sync).
// B LDS layout: row n (512 B), 16B slot s at byte n*512 + ((s^(n&7))<<4).

template <bool AF32>
__global__ __launch_bounds__(1024) void gemm_stream_t(const void* __restrict__ Araw,
                                                      const unsigned short* __restrict__ Bt,
                                                      unsigned short* __restrict__ C,
                                                      const float* __restrict__ dis,
                                                      int M, int ntiles) {
  __shared__ unsigned short Bs[256 * 256];  // 128 KB
  const int tid = threadIdx.x;

  // stage B: thread t covers row n=t>>2, slots s = (t&3) + 4*it, it=0..7
  {
    const int n = tid >> 2;
    const int sb = tid & 3;
    const unsigned short* src = Bt + (size_t)n * 256;
#pragma unroll
    for (int it = 0; it < 8; ++it) {
      int s = sb + 4 * it;
      u16x8 v = *(const u16x8*)(src + s * 8);
      *(u16x8*)((char*)Bs + n * 512 + ((s ^ (n & 7)) << 4)) = v;
    }
  }
  __syncthreads();  // the only barrier

  const int lane = tid & 63;
  const int r15 = lane & 15;
  const int cq = lane >> 4;
  const int gw = blockIdx.x * 16 + (tid >> 6);
  const int nw = gridDim.x * 16;

  for (int mt = gw; mt < ntiles; mt += nw) {
    const int m0 = mt * 16;
    const int arow = min(m0 + r15, M - 1);

    // load all 8 A k-frags up front (8 loads in flight)
    bf16x8 a[8];
    if constexpr (AF32) {
      const float* ap = (const float*)Araw + (size_t)arow * 256 + cq * 8;
#pragma unroll
      for (int kt = 0; kt < 8; ++kt) {
        float4 f0 = *(const float4*)(ap + kt * 32);
        float4 f1 = *(const float4*)(ap + kt * 32 + 4);
        u16x8 t;
        t[0] = f2bf(f0.x); t[1] = f2bf(f0.y); t[2] = f2bf(f0.z); t[3] = f2bf(f0.w);
        t[4] = f2bf(f1.x); t[5] = f2bf(f1.y); t[6] = f2bf(f1.z); t[7] = f2bf(f1.w);
        a[kt] = (bf16x8)t;
      }
    } else {
      const unsigned short* ap = (const unsigned short*)Araw + (size_t)arow * 256 + cq * 8;
#pragma unroll
      for (int kt = 0; kt < 8; ++kt) a[kt] = *(const bf16x8*)(ap + kt * 32);
    }

    f32x4 acc[16];
#pragma unroll
    for (int j = 0; j < 16; ++j)
#pragma unroll
      for (int r = 0; r < 4; ++r) acc[j][r] = 0.f;

#pragma unroll
    for (int kt = 0; kt < 8; ++kt) {
#pragma unroll
      for (int j = 0; j < 16; ++j) {
        int n = j * 16 + r15;
        int s = kt * 4 + cq;
        bf16x8 b = *(const bf16x8*)((char*)Bs + n * 512 + ((s ^ (n & 7)) << 4));
        acc[j] = __builtin_amdgcn_mfma_f32_16x16x32_bf16(a[kt], b, acc[j], 0, 0, 0);
      }
    }

    // epilogue: D row = m0 + cq*4 + r, col = j*16 + r15 ; C = f2bf(dis[row]*acc)
    float dv[4];
#pragma unroll
    for (int r = 0; r < 4; ++r) {
      int row = m0 + cq * 4 + r;
      dv[r] = (row < M) ? dis[row] : 0.f;
    }
#pragma unroll
    for (int r = 0; r < 4; ++r) {
      int row = m0 + cq * 4 + r;
      if (row < M) {
        unsigned short* cp = C + (size_t)row * 256 + r15;
#pragma unroll
        for (int j = 0; j < 16; ++j) cp[j * 16] = f2bf(dv[r] * acc[j][r]);
      }
    }
  }
}

// ---------------- aggregation (pre-scaled H'): one wave per node ----------------
// O[v] = relu( dis[v] * (sum_{e:dst=v} H'[src] + H'[v]) + b ),  H' = dis*H

__global__ __launch_bounds__(TPB) void aggregate_bf_k(const unsigned short* __restrict__ H,
                                                      unsigned short* __restrict__ O,
                                                      const int* __restrict__ row_ptr,
                                                      const int* __restrict__ col_src,
                                                      const float* __restrict__ dis,
                                                      const float* __restrict__ bias,
                                                      int N) {
  int wid = (blockIdx.x * TPB + threadIdx.x) >> 6;
  int lane = threadIdx.x & 63;
  if (wid >= N) return;
  int beg = row_ptr[wid], end = row_ptr[wid + 1];

  float p0 = 0.f, p1 = 0.f, p2 = 0.f, p3 = 0.f;
  float q0 = 0.f, q1 = 0.f, q2 = 0.f, q3 = 0.f;
  float r0 = 0.f, r1 = 0.f, r2 = 0.f, r3 = 0.f;
  float t0 = 0.f, t1 = 0.f, t2 = 0.f, t3 = 0.f;

  int e = beg;
  for (; e + 4 <= end; e += 4) {
    int s0 = col_src[e + 0];
    int s1 = col_src[e + 1];
    int s2 = col_src[e + 2];
    int s3 = col_src[e + 3];
    ushort4 h0 = *(const ushort4*)(H + (size_t)s0 * 256 + lane * 4);
    ushort4 h1 = *(const ushort4*)(H + (size_t)s1 * 256 + lane * 4);
    ushort4 h2 = *(const ushort4*)(H + (size_t)s2 * 256 + lane * 4);
    ushort4 h3 = *(const ushort4*)(H + (size_t)s3 * 256 + lane * 4);
    p0 += bf2f(h0.x); p1 += bf2f(h0.y); p2 += bf2f(h0.z); p3 += bf2f(h0.w);
    q0 += bf2f(h1.x); q1 += bf2f(h1.y); q2 += bf2f(h1.z); q3 += bf2f(h1.w);
    r0 += bf2f(h2.x); r1 += bf2f(h2.y); r2 += bf2f(h2.z); r3 += bf2f(h2.w);
    t0 += bf2f(h3.x); t1 += bf2f(h3.y); t2 += bf2f(h3.z); t3 += bf2f(h3.w);
  }
  for (; e < end; ++e) {
    int s = col_src[e];
    ushort4 h = *(const ushort4*)(H + (size_t)s * 256 + lane * 4);
    p0 += bf2f(h.x); p1 += bf2f(h.y); p2 += bf2f(h.z); p3 += bf2f(h.w);
  }

  ushort4 hv = *(const ushort4*)(H + (size_t)wid * 256 + lane * 4);
  p0 += bf2f(hv.x); p1 += bf2f(hv.y); p2 += bf2f(hv.z); p3 += bf2f(hv.w);

  float s0 = (p0 + q0) + (r0 + t0);
  float s1 = (p1 + q1) + (r1 + t1);
  float s2 = (p2 + q2) + (r2 + t2);
  float s3 = (p3 + q3) + (r3 + t3);

  float dv = dis[wid];
  float4 b = *(const float4*)(bias + lane * 4);
  ushort4 o;
  o.x = f2bf(fmaxf(fmaf(dv, s0, b.x), 0.f));
  o.y = f2bf(fmaxf(fmaf(dv, s1, b.y), 0.f));
  o.z = f2bf(fmaxf(fmaf(dv, s2, b.z), 0.f));
  o.w = f2bf(fmaxf(fmaf(dv, s3, b.w), 0.f));
  *(ushort4*)(O + (size_t)wid * 256 + lane * 4) = o;
}

// ---------------- streaming output layer: logits = H @ Wot^T + bo ; log_softmax ----
// Wot (64x256 bf16 = 32 KB) in LDS; 8 waves/block; each wave owns one 16-row
// tile: 32 MFMA, in-register 16-lane-group softmax, coalesced f32 stores.

__global__ __launch_bounds__(512) void outgemm_stream_k(const unsigned short* __restrict__ H,
                                                        const unsigned short* __restrict__ Wot,
                                                        const float* __restrict__ bo,
                                                        float* __restrict__ out,
                                                        int M, int ntiles) {
  __shared__ unsigned short Bs[64 * 256];  // 32 KB
  const int tid = threadIdx.x;

  // stage: thread t covers row n=t>>3 (0..63), slots s=(t&7)+8*it, it=0..3
  {
    const int n = tid >> 3;
    const int sb = tid & 7;
    const unsigned short* src = Wot + (size_t)n * 256;
#pragma unroll
    for (int it = 0; it < 4; ++it) {
      int s = sb + 8 * it;
      u16x8 v = *(const u16x8*)(src + s * 8);
      *(u16x8*)((char*)Bs + n * 512 + ((s ^ (n & 7)) << 4)) = v;
    }
  }
  __syncthreads();

  const int lane = tid & 63;
  const int r15 = lane & 15;
  const int cq = lane >> 4;
  const int mt = blockIdx.x * 8 + (tid >> 6);
  if (mt >= ntiles) return;
  const int m0 = mt * 16;
  const int arow = min(m0 + r15, M - 1);

  bf16x8 a[8];
  {
    const unsigned short* ap = H + (size_t)arow * 256 + cq * 8;
#pragma unroll
    for (int kt = 0; kt < 8; ++kt) a[kt] = *(const bf16x8*)(ap + kt * 32);
  }

  f32x4 acc[4];
#pragma unroll
  for (int j = 0; j < 4; ++j)
#pragma unroll
    for (int r = 0; r < 4; ++r) acc[j][r] = 0.f;

#pragma unroll
  for (int kt = 0; kt < 8; ++kt) {
#pragma unroll
    for (int j = 0; j < 4; ++j) {
      int n = j * 16 + r15;
      int s = kt * 4 + cq;
      bf16x8 b = *(const bf16x8*)((char*)Bs + n * 512 + ((s ^ (n & 7)) << 4));
      acc[j] = __builtin_amdgcn_mfma_f32_16x16x32_bf16(a[kt], b, acc[j], 0, 0, 0);
    }
  }

  // bias (col = j*16 + r15)
#pragma unroll
  for (int j = 0; j < 4; ++j) {
    float bj = bo[j * 16 + r15];
#pragma unroll
    for (int r = 0; r < 4; ++r) acc[j][r] += bj;
  }

  // per physical row (= m0 + cq*4 + r): 64 cols live as acc[0..3][r] across the
  // 16 lanes sharing cq. Reduce with shfl_xor 1,2,4,8 (stays in 16-lane group).
#pragma unroll
  for (int r = 0; r < 4; ++r) {
    int row = m0 + cq * 4 + r;
    float mx = fmaxf(fmaxf(acc[0][r], acc[1][r]), fmaxf(acc[2][r], acc[3][r]));
#pragma unroll
    for (int o = 1; o <= 8; o <<= 1) mx = fmaxf(mx, __shfl_xor(mx, o, 64));
    float se = expf(acc[0][r] - mx) + expf(acc[1][r] - mx) +
               expf(acc[2][r] - mx) + expf(acc[3][r] - mx);
#pragma unroll
    for (int o = 1; o <= 8; o <<= 1) se += __shfl_xor(se, o, 64);
    float ls = logf(se);
    if (row < M) {
      float* op = out + (size_t)row * 64 + r15;
#pragma unroll
      for (int j = 0; j < 4; ++j) op[j * 16] = (acc[j][r] - mx) - ls;
    }
  }
}

// ---------------- launch ----------------

extern "C" void kernel_launch(void* const* d_in, const int* in_sizes, int n_in,
                              void* d_out, int out_size, void* d_ws, size_t ws_size,
                              hipStream_t stream) {
  const float* x = (const float*)d_in[0];
  const int* ei = (const int*)d_in[1];
  const float* W1 = (const float*)d_in[2];
  const float* b1 = (const float*)d_in[3];
  const float* W2 = (const float*)d_in[4];
  const float* b2 = (const float*)d_in[5];
  const float* Wo = (const float*)d_in[6];
  const float* bo = (const float*)d_in[7];
  float* out = (float*)d_out;

  const int Dh = 256;
  const int N = in_sizes[0] / Dh;
  const int E = in_sizes[1] / 2;
  const int* srcv = ei;
  const int* dstv = ei + E;

  char* p = (char*)d_ws;
  auto take = [&](size_t bytes) {
    char* r = p;
    p += (bytes + 255) & ~(size_t)255;
    return r;
  };
  unsigned short* hbuf1 = (unsigned short*)take((size_t)N * Dh * 2);
  unsigned short* hbuf2 = (unsigned short*)take((size_t)N * Dh * 2);
  unsigned short* Wt1 = (unsigned short*)take(256 * 256 * 2);
  unsigned short* Wt2 = (unsigned short*)take(256 * 256 * 2);
  unsigned short* Wot = (unsigned short*)take(64 * 256 * 2);
  float* dis = (float*)take((size_t)N * 4);
  int* cnt = (int*)take((size_t)N * 4);
  int* row_ptr = (int*)take((size_t)(N + 1) * 4);
  int* cursor = (int*)take((size_t)N * 4);
  int* col_src = (int*)take((size_t)E * 4);
  int* blk_sums = (int*)take(4096 * 4);

  int NB = (N + 1023) / 1024;

  wt_k<<<256, TPB, 0, stream>>>(W1, Wt1);
  wt_k<<<256, TPB, 0, stream>>>(W2, Wt2);
  wot_k<<<64, TPB, 0, stream>>>(Wo, Wot);
  zero_cnt_k<<<(N + TPB - 1) / TPB, TPB, 0, stream>>>(cnt, N);
  count_k<<<(E + TPB - 1) / TPB, TPB, 0, stream>>>(dstv, cnt, E);
  scan1_k<<<NB, TPB, 0, stream>>>(cnt, row_ptr, blk_sums, N);
  scan2_k<<<1, TPB, 0, stream>>>(blk_sums, NB);
  finalize_k<<<(N + TPB - 1) / TPB, TPB, 0, stream>>>(row_ptr, blk_sums, cursor, cnt, dis, N, E);
  fill_k<<<(E + TPB - 1) / TPB, TPB, 0, stream>>>(srcv, dstv, cursor, col_src, E);

  const int ntiles = (N + 15) / 16;  // 6250

  // layer 1 (reads f32 x directly, outputs dis-scaled H')
  gemm_stream_t<true><<<256, 1024, 0, stream>>>((const void*)x, Wt1, hbuf1, dis, N, ntiles);
  aggregate_bf_k<<<(N + 3) / 4, TPB, 0, stream>>>(hbuf1, hbuf2, row_ptr, col_src, dis, b1, N);
  // layer 2
  gemm_stream_t<false><<<256, 1024, 0, stream>>>((const void*)hbuf2, Wt2, hbuf1, dis, N, ntiles);
  aggregate_bf_k<<<(N + 3) / 4, TPB, 0, stream>>>(hbuf1, hbuf2, row_ptr, col_src, dis, b2, N);
  // output layer + fused log_softmax
  outgemm_stream_k<<<(ntiles + 7) / 8, 512, 0, stream>>>(hbuf2, Wot, bo, out, N, ntiles);
}